// Round 2
// baseline (608.947 us; speedup 1.0000x reference)
//
#include <hip/hip_runtime.h>
#include <hip/hip_bf16.h>
#include <math.h>

// MultiHeadLatentAttention: B=8 S=4096 D=1024 H=16 dh=64 L=64
// Pipeline: cast->bf16, rope table, lq MFMA GEMM (+rope,+1/8 scale),
// fused K/V MFMA GEMM (bias + K-rope in epilogue), flash attention partials,
// combine, out-proj (fp32).

typedef __attribute__((ext_vector_type(8))) short bf16x8;   // 8 x bf16 (4 VGPR)
typedef __attribute__((ext_vector_type(4))) float f32x4;    // MFMA C/D

#define MFMA16(a, b, c) __builtin_amdgcn_mfma_f32_16x16x32_bf16((a), (b), (c), 0, 0, 0)

__device__ __forceinline__ unsigned short f2bf(float f) {
  unsigned int u = __float_as_uint(f);
  u = (u + 0x7fffu + ((u >> 16) & 1u)) >> 16;   // RNE
  return (unsigned short)u;
}

__device__ __forceinline__ void gload_lds16(const void* g, void* l) {
  __builtin_amdgcn_global_load_lds((const __attribute__((address_space(1))) void*)g,
                                   (__attribute__((address_space(3))) void*)l,
                                   16, 0, 0);
}

// ---------------------------------------------------------------- cast f32->bf16
__global__ __launch_bounds__(256) void cast_f32_bf16(const float* __restrict__ in,
                                                     unsigned short* __restrict__ out,
                                                     int n4) {
  int i = blockIdx.x * 256 + threadIdx.x;
  const int stride = gridDim.x * 256;
  for (; i < n4; i += stride) {
    const float4 v = ((const float4*)in)[i];
    ushort4 o;
    o.x = f2bf(v.x); o.y = f2bf(v.y); o.z = f2bf(v.z); o.w = f2bf(v.w);
    ((ushort4*)out)[i] = o;
  }
}

// ---------------------------------------------------------------- rope cos/sin table [S=4096][32]
__global__ __launch_bounds__(256) void rope_table_kernel(float2* __restrict__ cs) {
  const int id = blockIdx.x * 256 + threadIdx.x;   // 131072
  const int s = id >> 5, p = id & 31;
  const float inv = (float)pow(10000.0, -(double)(2 * p) / 64.0);
  const float ang = (float)s * inv;
  cs[id] = make_float2(cosf(ang), sinf(ang));
}

// ---------------------------------------------------------------- latent Q via MFMA:
// lq(64x1024) = latents @ q_w.T + q_b, rope(pos=l), *0.125 -> bf16
// grid 8 blocks (n0 = blk*128), 4 waves, wave covers 32 n-cols.
__global__ __launch_bounds__(256) void lq_mfma_kernel(
    const unsigned short* __restrict__ latbf, const unsigned short* __restrict__ qwbf,
    const float* __restrict__ qb, const float2* __restrict__ cs,
    unsigned short* __restrict__ lqbf) {
  __shared__ unsigned short As[64 * 64];    // latents [64 l][64 k]
  __shared__ unsigned short Bs[128 * 64];   // q_w     [128 n][64 k]
  const int tid = threadIdx.x;
  const int lane = tid & 63, w = tid >> 6;
  const int cl = lane & 15, g8 = (lane >> 4) * 8, g4 = (lane >> 4) * 4;
  const int n0 = (int)blockIdx.x * 128;
  f32x4 acc[4][2] = {};
  for (int ks = 0; ks < 16; ++ks) {
    const int k0 = ks * 64;
    if (ks) __syncthreads();
#pragma unroll
    for (int i = 0; i < 2; ++i) {
      const int e = i * 2048 + tid * 8;
      gload_lds16(latbf + (size_t)(e >> 6) * 1024 + k0 + (e & 63), &As[i * 2048 + w * 512]);
    }
#pragma unroll
    for (int i = 0; i < 4; ++i) {
      const int e = i * 2048 + tid * 8;
      gload_lds16(qwbf + (size_t)(n0 + (e >> 6)) * 1024 + k0 + (e & 63), &Bs[i * 2048 + w * 512]);
    }
    __syncthreads();
#pragma unroll
    for (int kk = 0; kk < 2; ++kk) {
      bf16x8 af[4], bfr[2];
#pragma unroll
      for (int t = 0; t < 4; ++t)
        af[t] = *(const bf16x8*)&As[(t * 16 + cl) * 64 + kk * 32 + g8];
#pragma unroll
      for (int t = 0; t < 2; ++t)
        bfr[t] = *(const bf16x8*)&Bs[(w * 32 + t * 16 + cl) * 64 + kk * 32 + g8];
#pragma unroll
      for (int i = 0; i < 4; ++i)
#pragma unroll
        for (int j = 0; j < 2; ++j)
          acc[i][j] = MFMA16(af[i], bfr[j], acc[i][j]);
    }
  }
#pragma unroll
  for (int i = 0; i < 4; ++i)
#pragma unroll
    for (int j = 0; j < 2; ++j) {
      const int colg = n0 + w * 32 + j * 16 + cl;
      const float bv = qb[colg];
      const int p = (colg & 63) >> 1;
#pragma unroll
      for (int r = 0; r < 4; ++r) {
        const int l = i * 16 + g4 + r;
        float v = acc[i][j][r] + bv;
        const float2 c2 = cs[l * 32 + p];
        const float other = __shfl_xor(v, 1);
        v = (colg & 1) ? fmaf(v, c2.x, other * c2.y) : fmaf(v, c2.x, -other * c2.y);
        lqbf[l * 1024 + colg] = f2bf(v * 0.125f);
      }
    }
}

// ---------------------------------------------------------------- fused K/V projection GEMM (bf16 MFMA, 128x128 tile, BK=64)
// C[m,n] = sum_k X[m,k]*W[n,k] + bias[n]; n<1024 -> K (rope applied), else V.
__global__ __launch_bounds__(256) void kv_proj_kernel(
    const unsigned short* __restrict__ xbf,
    const unsigned short* __restrict__ kwbf, const unsigned short* __restrict__ vwbf,
    const float* __restrict__ kb, const float* __restrict__ vb,
    const float2* __restrict__ cs,
    unsigned short* __restrict__ Kbf, unsigned short* __restrict__ Vbf) {
  __shared__ unsigned short As[128 * 64];
  __shared__ unsigned short Bs[128 * 64];
  const int tid = threadIdx.x;
  const int lane = tid & 63;
  const int w = tid >> 6;
  const int wr = w >> 1, wc = w & 1;
  const int cl = lane & 15, g8 = (lane >> 4) * 8, g4 = (lane >> 4) * 4;
  // XCD-aware bijective swizzle: 4096 blocks % 8 == 0
  const int bid = (int)blockIdx.x;
  const int swz = (bid & 7) * 512 + (bid >> 3);
  const int m0 = (swz >> 4) * 128;   // 256 m-blocks
  const int n0 = (swz & 15) * 128;   // 16 n-blocks (0..2047)
  const bool isK = n0 < 1024;
  const unsigned short* wbf = isK ? kwbf : vwbf;
  const int nl = isK ? n0 : n0 - 1024;
  const int ldsb = w * 512;

  f32x4 acc[4][4] = {};

  for (int ks = 0; ks < 16; ++ks) {
    const int k0 = ks * 64;
    if (ks) __syncthreads();
#pragma unroll
    for (int i = 0; i < 4; ++i) {
      const int e = i * 2048 + tid * 8;
      const int row = e >> 6, col = e & 63;
      gload_lds16(xbf + (size_t)(m0 + row) * 1024 + k0 + col, &As[i * 2048 + ldsb]);
    }
#pragma unroll
    for (int i = 0; i < 4; ++i) {
      const int e = i * 2048 + tid * 8;
      const int row = e >> 6, col = e & 63;
      gload_lds16(wbf + (size_t)(nl + row) * 1024 + k0 + col, &Bs[i * 2048 + ldsb]);
    }
    __syncthreads();   // compiler drains vmcnt before barrier
#pragma unroll
    for (int kk = 0; kk < 2; ++kk) {
      bf16x8 af[4], bfr[4];
#pragma unroll
      for (int t = 0; t < 4; ++t)
        af[t] = *(const bf16x8*)&As[(wr * 64 + t * 16 + cl) * 64 + kk * 32 + g8];
#pragma unroll
      for (int t = 0; t < 4; ++t)
        bfr[t] = *(const bf16x8*)&Bs[(wc * 64 + t * 16 + cl) * 64 + kk * 32 + g8];
#pragma unroll
      for (int i = 0; i < 4; ++i)
#pragma unroll
        for (int j = 0; j < 4; ++j)
          acc[i][j] = MFMA16(af[i], bfr[j], acc[i][j]);
    }
  }

  const float* bias = isK ? kb : vb;
  unsigned short* outp = isK ? Kbf : Vbf;
#pragma unroll
  for (int i = 0; i < 4; ++i) {
#pragma unroll
    for (int j = 0; j < 4; ++j) {
      const int colg = nl + wc * 64 + j * 16 + cl;    // feature 0..1023
      const float bv = bias[colg];
#pragma unroll
      for (int r = 0; r < 4; ++r) {
        const int m = m0 + wr * 64 + i * 16 + g4 + r;
        float v = acc[i][j][r] + bv;
        if (isK) {   // rope: pairs are adjacent n -> adjacent lanes
          const int s = m & 4095;
          const int p = (colg & 63) >> 1;
          const float2 c2 = cs[s * 32 + p];
          const float other = __shfl_xor(v, 1);
          v = (colg & 1) ? fmaf(v, c2.x, other * c2.y) : fmaf(v, c2.x, -other * c2.y);
        }
        outp[(size_t)m * 1024 + colg] = f2bf(v);
      }
    }
  }
}

// ---------------------------------------------------------------- flash attention partials
// grid = B*H*NCH (NCH=4, chunk=1024). 4 waves/block, each wave owns 32-s stripes.
__global__ __launch_bounds__(256) void attn_kernel(
    const unsigned short* __restrict__ lqbf,
    const unsigned short* __restrict__ Kbf, const unsigned short* __restrict__ Vbf,
    float* __restrict__ Opart, float* __restrict__ ml) {
  __shared__ unsigned short Qs[64 * 64];
  __shared__ unsigned short Ks[4][32 * 64];
  __shared__ unsigned short Vs[4][32 * 64];
  __shared__ unsigned short Pb[4][64 * 32];
  const int tid = threadIdx.x;
  const int w = tid >> 6, lane = tid & 63;
  const int cl = lane & 15, g = lane >> 4, g8 = g * 8, g4 = g * 4;
  const int gid = blockIdx.x;
  const int c = gid & 3;
  const int h = (gid >> 2) & 15;
  const int b = gid >> 6;

#pragma unroll
  for (int i = 0; i < 2; ++i) {
    const int e = i * 2048 + tid * 8;
    const int l = e >> 6, d = e & 63;
    *(uint4*)&Qs[e] = *(const uint4*)&lqbf[l * 1024 + h * 64 + d];
  }
  __syncthreads();
  bf16x8 qf[4][2];
#pragma unroll
  for (int li = 0; li < 4; ++li)
#pragma unroll
    for (int kk = 0; kk < 2; ++kk)
      qf[li][kk] = *(const bf16x8*)&Qs[(li * 16 + cl) * 64 + kk * 32 + g8];

  float m_r[4][4], l_r[4][4];
  f32x4 acc_o[4][4] = {};
#pragma unroll
  for (int li = 0; li < 4; ++li)
#pragma unroll
    for (int r = 0; r < 4; ++r) { m_r[li][r] = -INFINITY; l_r[li][r] = 0.f; }

  const size_t kvbase = ((size_t)(b * 4096)) * 1024 + h * 64;
  for (int t = 0; t < 8; ++t) {
    const int s0 = c * 1024 + t * 128 + w * 32;
    // stage K,V stripes (wave-private; same-wave DS ordering makes this safe)
#pragma unroll
    for (int i = 0; i < 4; ++i) {
      const int e = i * 512 + lane * 8;
      const int r = e >> 6, d = e & 63;
      const size_t ga = kvbase + (size_t)(s0 + r) * 1024 + d;
      *(uint4*)&Ks[w][e] = *(const uint4*)&Kbf[ga];
      *(uint4*)&Vs[w][e] = *(const uint4*)&Vbf[ga];
    }
    // QK^T: D[l=64][s=32]
    f32x4 sc[4][2] = {};
#pragma unroll
    for (int kk = 0; kk < 2; ++kk)
#pragma unroll
      for (int sj = 0; sj < 2; ++sj) {
        const bf16x8 kf = *(const bf16x8*)&Ks[w][(sj * 16 + cl) * 64 + kk * 32 + g8];
#pragma unroll
        for (int li = 0; li < 4; ++li)
          sc[li][sj] = MFMA16(qf[li][kk], kf, sc[li][sj]);
      }
    // online softmax over the 32 stripe columns
#pragma unroll
    for (int li = 0; li < 4; ++li) {
#pragma unroll
      for (int r = 0; r < 4; ++r) {
        const float v0 = sc[li][0][r], v1 = sc[li][1][r];
        float mx = fmaxf(v0, v1);
        mx = fmaxf(mx, __shfl_xor(mx, 1));
        mx = fmaxf(mx, __shfl_xor(mx, 2));
        mx = fmaxf(mx, __shfl_xor(mx, 4));
        mx = fmaxf(mx, __shfl_xor(mx, 8));
        const float mo = m_r[li][r];
        const float nm = fmaxf(mo, mx);
        const float p0 = __expf(v0 - nm);
        const float p1 = __expf(v1 - nm);
        const float f = __expf(mo - nm);
        m_r[li][r] = nm;
        float sp = p0 + p1;
        sp += __shfl_xor(sp, 1);
        sp += __shfl_xor(sp, 2);
        sp += __shfl_xor(sp, 4);
        sp += __shfl_xor(sp, 8);
        l_r[li][r] = l_r[li][r] * f + sp;
#pragma unroll
        for (int di = 0; di < 4; ++di) acc_o[li][di][r] *= f;
        const int lrow = li * 16 + g4 + r;
        Pb[w][lrow * 32 + cl] = f2bf(p0);
        Pb[w][lrow * 32 + 16 + cl] = f2bf(p1);
      }
    }
    // PV: acc_o[l][d] += P(64x32) * V(32x64)
    bf16x8 pa[4];
#pragma unroll
    for (int li = 0; li < 4; ++li)
      pa[li] = *(const bf16x8*)&Pb[w][(li * 16 + cl) * 32 + g8];
#pragma unroll
    for (int di = 0; di < 4; ++di) {
      bf16x8 bv;
#pragma unroll
      for (int e = 0; e < 8; ++e)
        bv[e] = (short)Vs[w][(g8 + e) * 64 + di * 16 + cl];
#pragma unroll
      for (int li = 0; li < 4; ++li)
        acc_o[li][di] = MFMA16(pa[li], bv, acc_o[li][di]);
    }
  }
  // write partials
  const int part = c * 4 + w;   // 0..15
  const size_t obase = (((size_t)(b * 16 + h)) * 16 + part) * 4096;
#pragma unroll
  for (int li = 0; li < 4; ++li)
#pragma unroll
    for (int di = 0; di < 4; ++di)
#pragma unroll
      for (int r = 0; r < 4; ++r)
        Opart[obase + (size_t)(li * 16 + g4 + r) * 64 + di * 16 + cl] = acc_o[li][di][r];
  if (cl == 0) {
    const size_t mb = (((size_t)(b * 16 + h)) * 16 + part) * 128;
#pragma unroll
    for (int li = 0; li < 4; ++li)
#pragma unroll
      for (int r = 0; r < 4; ++r) {
        ml[mb + li * 16 + g4 + r] = m_r[li][r];
        ml[mb + 64 + li * 16 + g4 + r] = l_r[li][r];
      }
  }
}

// ---------------------------------------------------------------- combine 16 partials per (b,h)
__global__ __launch_bounds__(256) void combine_kernel(
    const float* __restrict__ Opart, const float* __restrict__ ml,
    float* __restrict__ attn_out) {
  const int id = blockIdx.x * 256 + threadIdx.x;   // 524288
  const int d = id & 63;
  const int l = (id >> 6) & 63;
  const int h = (id >> 12) & 15;
  const int b = id >> 16;
  const size_t bh = (size_t)(b * 16 + h);
  float M = -INFINITY;
#pragma unroll
  for (int p = 0; p < 16; ++p) M = fmaxf(M, ml[(bh * 16 + p) * 128 + l]);
  float t = 0.f, acc = 0.f;
#pragma unroll
  for (int p = 0; p < 16; ++p) {
    const float mp = ml[(bh * 16 + p) * 128 + l];
    const float lp = ml[(bh * 16 + p) * 128 + 64 + l];
    const float wgt = __expf(mp - M);
    t += lp * wgt;
    acc += wgt * Opart[(bh * 16 + p) * 4096 + l * 64 + d];
  }
  attn_out[((size_t)(b * 64 + l)) * 1024 + h * 64 + d] = acc / t;
}

// ---------------------------------------------------------------- out projection: C[512,1024] = A@W.T + b (fp32)
__global__ __launch_bounds__(256) void out_proj_kernel(
    const float* __restrict__ A, const float* __restrict__ Wt,
    const float* __restrict__ bias, float* __restrict__ C) {
  __shared__ float As[32 * 33];
  __shared__ float Bs[64 * 33];
  const int tid = threadIdx.x;
  const int m0 = (int)(blockIdx.x & 15) * 32;
  const int n0 = (int)(blockIdx.x >> 4) * 64;
  const int r0 = (tid >> 4) * 2;
  const int c0 = (tid & 15) * 4;
  float acc[2][4] = {};
  for (int k0 = 0; k0 < 1024; k0 += 32) {
    if (k0) __syncthreads();
    {
      const int row = tid >> 3, col = (tid & 7) * 4;
      const float4 a4 = *(const float4*)&A[(size_t)(m0 + row) * 1024 + k0 + col];
      As[row * 33 + col] = a4.x; As[row * 33 + col + 1] = a4.y;
      As[row * 33 + col + 2] = a4.z; As[row * 33 + col + 3] = a4.w;
    }
#pragma unroll
    for (int i = 0; i < 2; ++i) {
      const int e = i * 1024 + tid * 4;
      const int row = e >> 5, col = e & 31;
      const float4 b4 = *(const float4*)&Wt[(size_t)(n0 + row) * 1024 + k0 + col];
      Bs[row * 33 + col] = b4.x; Bs[row * 33 + col + 1] = b4.y;
      Bs[row * 33 + col + 2] = b4.z; Bs[row * 33 + col + 3] = b4.w;
    }
    __syncthreads();
#pragma unroll
    for (int kk = 0; kk < 32; ++kk) {
      const float a0 = As[r0 * 33 + kk], a1 = As[(r0 + 1) * 33 + kk];
      float bv[4];
#pragma unroll
      for (int j = 0; j < 4; ++j) bv[j] = Bs[(c0 + j) * 33 + kk];
#pragma unroll
      for (int j = 0; j < 4; ++j) {
        acc[0][j] = fmaf(a0, bv[j], acc[0][j]);
        acc[1][j] = fmaf(a1, bv[j], acc[1][j]);
      }
    }
  }
#pragma unroll
  for (int i = 0; i < 2; ++i)
#pragma unroll
    for (int j = 0; j < 4; ++j)
      C[(size_t)(m0 + r0 + i) * 1024 + n0 + c0 + j] = acc[i][j] + bias[n0 + c0 + j];
}

// ----------------------------------------------------------------
extern "C" void kernel_launch(void* const* d_in, const int* in_sizes, int n_in,
                              void* d_out, int out_size, void* d_ws, size_t ws_size,
                              hipStream_t stream) {
  (void)in_sizes; (void)n_in; (void)out_size; (void)ws_size;
  const float* x = (const float*)d_in[0];
  const float* latents = (const float*)d_in[1];
  const float* q_w = (const float*)d_in[2];
  const float* q_b = (const float*)d_in[3];
  const float* k_w = (const float*)d_in[4];
  const float* k_b = (const float*)d_in[5];
  const float* v_w = (const float*)d_in[6];
  const float* v_b = (const float*)d_in[7];
  const float* out_w = (const float*)d_in[8];
  const float* out_b = (const float*)d_in[9];
  float* out = (float*)d_out;

  // workspace layout (~236 MiB total)
  char* ws = (char*)d_ws;
  size_t off = 0;
  auto alloc = [&](size_t bytes) {
    char* p = ws + off;
    off += (bytes + 255) & ~(size_t)255;
    return p;
  };
  unsigned short* xbf   = (unsigned short*)alloc(33554432ull * 2);
  unsigned short* kwbf  = (unsigned short*)alloc(1048576ull * 2);
  unsigned short* vwbf  = (unsigned short*)alloc(1048576ull * 2);
  unsigned short* qwbf  = (unsigned short*)alloc(1048576ull * 2);
  unsigned short* latbf = (unsigned short*)alloc(65536ull * 2);
  unsigned short* lqbf  = (unsigned short*)alloc(65536ull * 2);
  float2*         cs    = (float2*)alloc(4096ull * 32 * 8);
  unsigned short* Kbf   = (unsigned short*)alloc(33554432ull * 2);
  unsigned short* Vbf   = (unsigned short*)alloc(33554432ull * 2);
  float*          Opart = (float*)alloc(8ull * 16 * 16 * 4096 * 4);
  float*          mlbuf = (float*)alloc(8ull * 16 * 16 * 128 * 4);
  float*          attn_out = (float*)alloc(512ull * 1024 * 4);

  cast_f32_bf16<<<2048, 256, 0, stream>>>(x, xbf, 33554432 / 4);
  cast_f32_bf16<<<512, 256, 0, stream>>>(k_w, kwbf, 1048576 / 4);
  cast_f32_bf16<<<512, 256, 0, stream>>>(v_w, vwbf, 1048576 / 4);
  cast_f32_bf16<<<512, 256, 0, stream>>>(q_w, qwbf, 1048576 / 4);
  cast_f32_bf16<<<64, 256, 0, stream>>>(latents, latbf, 65536 / 4);
  rope_table_kernel<<<512, 256, 0, stream>>>(cs);
  lq_mfma_kernel<<<8, 256, 0, stream>>>(latbf, qwbf, q_b, cs, lqbf);
  kv_proj_kernel<<<4096, 256, 0, stream>>>(xbf, kwbf, vwbf, k_b, v_b, cs, Kbf, Vbf);
  attn_kernel<<<512, 256, 0, stream>>>(lqbf, Kbf, Vbf, Opart, mlbuf);
  combine_kernel<<<2048, 256, 0, stream>>>(Opart, mlbuf, attn_out);
  out_proj_kernel<<<256, 256, 0, stream>>>(attn_out, out_w, out_b, out);
}

// Round 4
// 590.332 us; speedup vs baseline: 1.0315x; 1.0315x over previous
//
#include <hip/hip_runtime.h>
#include <hip/hip_bf16.h>
#include <math.h>

// MultiHeadLatentAttention: B=8 S=4096 D=1024 H=16 dh=64 L=64
// cast->bf16, rope table, lq MFMA GEMM, 8-phase 256^2 K/V projection GEMM
// (counted vmcnt pipeline, bias+rope epilogue), flash attention partials,
// combine, out-proj (fp32).

typedef __attribute__((ext_vector_type(8))) short bf16x8;   // 8 x bf16 (4 VGPR)
typedef __attribute__((ext_vector_type(4))) float f32x4;    // MFMA C/D

#define MFMA16(a, b, c) __builtin_amdgcn_mfma_f32_16x16x32_bf16((a), (b), (c), 0, 0, 0)

__device__ __forceinline__ unsigned short f2bf(float f) {
  unsigned int u = __float_as_uint(f);
  u = (u + 0x7fffu + ((u >> 16) & 1u)) >> 16;   // RNE
  return (unsigned short)u;
}

__device__ __forceinline__ void gload_lds16(const void* g, void* l) {
  __builtin_amdgcn_global_load_lds((const __attribute__((address_space(1))) void*)g,
                                   (__attribute__((address_space(3))) void*)l,
                                   16, 0, 0);
}

// ---------------------------------------------------------------- cast f32->bf16
__global__ __launch_bounds__(256) void cast_f32_bf16(const float* __restrict__ in,
                                                     unsigned short* __restrict__ out,
                                                     int n4) {
  int i = blockIdx.x * 256 + threadIdx.x;
  const int stride = gridDim.x * 256;
  for (; i < n4; i += stride) {
    const float4 v = ((const float4*)in)[i];
    ushort4 o;
    o.x = f2bf(v.x); o.y = f2bf(v.y); o.z = f2bf(v.z); o.w = f2bf(v.w);
    ((ushort4*)out)[i] = o;
  }
}

// ---------------------------------------------------------------- rope cos/sin table [S=4096][32]
__global__ __launch_bounds__(256) void rope_table_kernel(float2* __restrict__ cs) {
  const int id = blockIdx.x * 256 + threadIdx.x;   // 131072
  const int s = id >> 5, p = id & 31;
  // 10000^(-p/32) = exp2(-p * log2(10000)/32); float path (no software double)
  const float inv = exp2f(-(float)p * 0.41524100875f);
  const float ang = (float)s * inv;
  cs[id] = make_float2(cosf(ang), sinf(ang));
}

// ---------------------------------------------------------------- latent Q via MFMA:
// lq(64x1024) = latents @ q_w.T + q_b, rope(pos=l), *0.125 -> bf16
__global__ __launch_bounds__(256) void lq_mfma_kernel(
    const unsigned short* __restrict__ latbf, const unsigned short* __restrict__ qwbf,
    const float* __restrict__ qb, const float2* __restrict__ cs,
    unsigned short* __restrict__ lqbf) {
  __shared__ unsigned short As[64 * 64];    // latents [64 l][64 k]
  __shared__ unsigned short Bs[128 * 64];   // q_w     [128 n][64 k]
  const int tid = threadIdx.x;
  const int lane = tid & 63, w = tid >> 6;
  const int cl = lane & 15, g8 = (lane >> 4) * 8, g4 = (lane >> 4) * 4;
  const int n0 = (int)blockIdx.x * 128;
  f32x4 acc[4][2] = {};
  for (int ks = 0; ks < 16; ++ks) {
    const int k0 = ks * 64;
    if (ks) __syncthreads();
#pragma unroll
    for (int i = 0; i < 2; ++i) {
      const int e = i * 2048 + tid * 8;
      gload_lds16(latbf + (size_t)(e >> 6) * 1024 + k0 + (e & 63), &As[i * 2048 + w * 512]);
    }
#pragma unroll
    for (int i = 0; i < 4; ++i) {
      const int e = i * 2048 + tid * 8;
      gload_lds16(qwbf + (size_t)(n0 + (e >> 6)) * 1024 + k0 + (e & 63), &Bs[i * 2048 + w * 512]);
    }
    __syncthreads();
#pragma unroll
    for (int kk = 0; kk < 2; ++kk) {
      bf16x8 af[4], bfr[2];
#pragma unroll
      for (int t = 0; t < 4; ++t)
        af[t] = *(const bf16x8*)&As[(t * 16 + cl) * 64 + kk * 32 + g8];
#pragma unroll
      for (int t = 0; t < 2; ++t)
        bfr[t] = *(const bf16x8*)&Bs[(w * 32 + t * 16 + cl) * 64 + kk * 32 + g8];
#pragma unroll
      for (int i = 0; i < 4; ++i)
#pragma unroll
        for (int j = 0; j < 2; ++j)
          acc[i][j] = MFMA16(af[i], bfr[j], acc[i][j]);
    }
  }
#pragma unroll
  for (int i = 0; i < 4; ++i)
#pragma unroll
    for (int j = 0; j < 2; ++j) {
      const int colg = n0 + w * 32 + j * 16 + cl;
      const float bv = qb[colg];
      const int p = (colg & 63) >> 1;
#pragma unroll
      for (int r = 0; r < 4; ++r) {
        const int l = i * 16 + g4 + r;
        float v = acc[i][j][r] + bv;
        const float2 c2 = cs[l * 32 + p];
        const float other = __shfl_xor(v, 1);
        v = (colg & 1) ? fmaf(v, c2.x, other * c2.y) : fmaf(v, c2.x, -other * c2.y);
        lqbf[l * 1024 + colg] = f2bf(v * 0.125f);
      }
    }
}

// ---------------------------------------------------------------- fused K/V projection GEMM
// 256x256 tile, BK=64, 8 waves (2M x 4N), deep pipeline with counted vmcnt.
// C[m,n] = sum_k X[m,k]*W[n,k] + bias[n]; n<1024 -> K (+rope), else V.
// LDS: 2 buffers x 4 half-slots (A-kk0, A-kk1, B-kk0, B-kk1), each [256 rows][32 k]
// bf16 (64B rows -> naturally bank-balanced frag reads). Stage order per tile:
// A0,B0,A1,B1; vmcnt(4) before each half's reads retires exactly the 2 halves
// about to be consumed; never vmcnt(0) in-loop.
__global__ __launch_bounds__(512, 2) void kv_proj_kernel(
    const unsigned short* __restrict__ xbf,
    const unsigned short* __restrict__ kwbf, const unsigned short* __restrict__ vwbf,
    const float* __restrict__ kb, const float* __restrict__ vb,
    const float2* __restrict__ cs,
    unsigned short* __restrict__ Kbf, unsigned short* __restrict__ Vbf) {
  __shared__ unsigned short lds[2][4][8192];   // 128 KiB
  const int tid = threadIdx.x;
  const int lane = tid & 63, w = tid >> 6;
  const int wm = w >> 2, wn = w & 3;
  const int cl = lane & 15, g8 = (lane >> 4) * 8, g4 = (lane >> 4) * 4;
  // XCD-aware bijective swizzle (1024 blocks % 8 == 0)
  const int bid = (int)blockIdx.x;
  const int swz = (bid & 7) * 128 + (bid >> 3);
  const int m0 = (swz >> 3) * 256;   // 128 m-tiles
  const int n0 = (swz & 7) * 256;    // 8 n-tiles over fused [K|V]
  const bool isK = n0 < 1024;
  const unsigned short* wbf = isK ? kwbf : vwbf;
  const int nl = isK ? n0 : n0 - 1024;

  // staging: granule G = j*512 + tid; row = G>>2 (+128 for j=1), elem-off = (tid&3)*8
  const int srow = tid >> 2;
  const int sg8 = (tid & 3) * 8;
  const unsigned short* srcA = xbf + (size_t)(m0 + srow) * 1024 + sg8;
  const unsigned short* srcB = wbf + (size_t)(nl + srow) * 1024 + sg8;
  const int ldso0 = w * 512;          // j=0 wave base (ushort idx)
  const int ldso1 = 4096 + w * 512;   // j=1

#define STAGE_A(nb_, slot_, koff_) do {                                   \
    gload_lds16(srcA + (koff_), &lds[nb_][slot_][ldso0]);                 \
    gload_lds16(srcA + 131072 + (koff_), &lds[nb_][slot_][ldso1]); } while (0)
#define STAGE_B(nb_, slot_, koff_) do {                                   \
    gload_lds16(srcB + (koff_), &lds[nb_][slot_][ldso0]);                 \
    gload_lds16(srcB + 131072 + (koff_), &lds[nb_][slot_][ldso1]); } while (0)

  const int rdA = (wm * 128 + cl) * 32 + g8;   // frag-read base (A rows)
  const int rdB = (wn * 64 + cl) * 32 + g8;    // frag-read base (B rows)

  f32x4 acc[8][4] = {};

  // prologue: tile 0, issue order A0,B0,A1,B1 (2 loads each)
  STAGE_A(0, 0, 0);
  STAGE_B(0, 2, 0);
  STAGE_A(0, 1, 32);
  STAGE_B(0, 3, 32);

#pragma unroll 2
  for (int t = 0; t < 16; ++t) {
    const int cb = t & 1, nb = cb ^ 1;
    const int tn = (t < 15) ? t + 1 : 15;   // last iter re-stages (never read)
    const int kn = tn * 64;
#pragma unroll
    for (int kk = 0; kk < 2; ++kk) {
      // halves (A-kk, B-kk) of tile t are the 2 oldest in-flight stage pairs
      asm volatile("s_waitcnt vmcnt(4)" ::: "memory");
      __builtin_amdgcn_s_barrier();
      asm volatile("" ::: "memory");
      bf16x8 aF[4], bF[4];
#pragma unroll
      for (int x = 0; x < 4; ++x)
        aF[x] = *(const bf16x8*)&lds[cb][kk][rdA + x * 512];
#pragma unroll
      for (int x = 0; x < 4; ++x)
        bF[x] = *(const bf16x8*)&lds[cb][2 + kk][rdB + x * 512];
      STAGE_A(nb, kk, kn + kk * 32);
      __builtin_amdgcn_s_setprio(1);
#pragma unroll
      for (int mf = 0; mf < 4; ++mf)
#pragma unroll
        for (int nf = 0; nf < 4; ++nf)
          acc[mf][nf] = MFMA16(aF[mf], bF[nf], acc[mf][nf]);
      __builtin_amdgcn_s_setprio(0);
      bf16x8 aG[4];
#pragma unroll
      for (int x = 0; x < 4; ++x)
        aG[x] = *(const bf16x8*)&lds[cb][kk][rdA + (4 + x) * 512];
      STAGE_B(nb, 2 + kk, kn + kk * 32);
      __builtin_amdgcn_s_setprio(1);
#pragma unroll
      for (int mf = 0; mf < 4; ++mf)
#pragma unroll
        for (int nf = 0; nf < 4; ++nf)
          acc[4 + mf][nf] = MFMA16(aG[mf], bF[nf], acc[4 + mf][nf]);
      __builtin_amdgcn_s_setprio(0);
    }
  }
  asm volatile("s_waitcnt vmcnt(0)" ::: "memory");   // drain before exit (LDS teardown)
#undef STAGE_A
#undef STAGE_B

  const float* bias = isK ? kb : vb;
  unsigned short* outp = isK ? Kbf : Vbf;
#pragma unroll
  for (int mf = 0; mf < 8; ++mf) {
#pragma unroll
    for (int nf = 0; nf < 4; ++nf) {
      const int colg = nl + wn * 64 + nf * 16 + cl;   // feature 0..1023
      const float bv = bias[colg];
#pragma unroll
      for (int r = 0; r < 4; ++r) {
        const int m = m0 + wm * 128 + mf * 16 + g4 + r;
        float v = acc[mf][nf][r] + bv;
        if (isK) {   // rope: adjacent features live in adjacent lanes
          const int s = m & 4095;
          const int p = (colg & 63) >> 1;
          const float2 c2 = cs[s * 32 + p];
          const float other = __shfl_xor(v, 1);
          v = (colg & 1) ? fmaf(v, c2.x, other * c2.y) : fmaf(v, c2.x, -other * c2.y);
        }
        outp[(size_t)m * 1024 + colg] = f2bf(v);
      }
    }
  }
}

// ---------------------------------------------------------------- flash attention partials
// grid = B*H*NCH (NCH=4, chunk=1024). 4 waves/block, each wave owns 32-s stripes.
__global__ __launch_bounds__(256) void attn_kernel(
    const unsigned short* __restrict__ lqbf,
    const unsigned short* __restrict__ Kbf, const unsigned short* __restrict__ Vbf,
    float* __restrict__ Opart, float* __restrict__ ml) {
  __shared__ unsigned short Qs[64 * 64];
  __shared__ unsigned short Ks[4][32 * 64];
  __shared__ unsigned short Vs[4][32 * 64];
  __shared__ unsigned short Pb[4][64 * 32];
  const int tid = threadIdx.x;
  const int w = tid >> 6, lane = tid & 63;
  const int cl = lane & 15, g = lane >> 4, g8 = g * 8, g4 = g * 4;
  const int gid = blockIdx.x;
  const int c = gid & 3;
  const int h = (gid >> 2) & 15;
  const int b = gid >> 6;

#pragma unroll
  for (int i = 0; i < 2; ++i) {
    const int e = i * 2048 + tid * 8;
    const int l = e >> 6, d = e & 63;
    *(uint4*)&Qs[e] = *(const uint4*)&lqbf[l * 1024 + h * 64 + d];
  }
  __syncthreads();
  bf16x8 qf[4][2];
#pragma unroll
  for (int li = 0; li < 4; ++li)
#pragma unroll
    for (int kk = 0; kk < 2; ++kk)
      qf[li][kk] = *(const bf16x8*)&Qs[(li * 16 + cl) * 64 + kk * 32 + g8];

  float m_r[4][4], l_r[4][4];
  f32x4 acc_o[4][4] = {};
#pragma unroll
  for (int li = 0; li < 4; ++li)
#pragma unroll
    for (int r = 0; r < 4; ++r) { m_r[li][r] = -INFINITY; l_r[li][r] = 0.f; }

  const size_t kvbase = ((size_t)(b * 4096)) * 1024 + h * 64;
  for (int t = 0; t < 8; ++t) {
    const int s0 = c * 1024 + t * 128 + w * 32;
#pragma unroll
    for (int i = 0; i < 4; ++i) {
      const int e = i * 512 + lane * 8;
      const int r = e >> 6, d = e & 63;
      const size_t ga = kvbase + (size_t)(s0 + r) * 1024 + d;
      *(uint4*)&Ks[w][e] = *(const uint4*)&Kbf[ga];
      *(uint4*)&Vs[w][e] = *(const uint4*)&Vbf[ga];
    }
    f32x4 sc[4][2] = {};
#pragma unroll
    for (int kk = 0; kk < 2; ++kk)
#pragma unroll
      for (int sj = 0; sj < 2; ++sj) {
        const bf16x8 kf = *(const bf16x8*)&Ks[w][(sj * 16 + cl) * 64 + kk * 32 + g8];
#pragma unroll
        for (int li = 0; li < 4; ++li)
          sc[li][sj] = MFMA16(qf[li][kk], kf, sc[li][sj]);
      }
#pragma unroll
    for (int li = 0; li < 4; ++li) {
#pragma unroll
      for (int r = 0; r < 4; ++r) {
        const float v0 = sc[li][0][r], v1 = sc[li][1][r];
        float mx = fmaxf(v0, v1);
        mx = fmaxf(mx, __shfl_xor(mx, 1));
        mx = fmaxf(mx, __shfl_xor(mx, 2));
        mx = fmaxf(mx, __shfl_xor(mx, 4));
        mx = fmaxf(mx, __shfl_xor(mx, 8));
        const float mo = m_r[li][r];
        const float nm = fmaxf(mo, mx);
        const float p0 = __expf(v0 - nm);
        const float p1 = __expf(v1 - nm);
        const float f = __expf(mo - nm);
        m_r[li][r] = nm;
        float sp = p0 + p1;
        sp += __shfl_xor(sp, 1);
        sp += __shfl_xor(sp, 2);
        sp += __shfl_xor(sp, 4);
        sp += __shfl_xor(sp, 8);
        l_r[li][r] = l_r[li][r] * f + sp;
#pragma unroll
        for (int di = 0; di < 4; ++di) acc_o[li][di][r] *= f;
        const int lrow = li * 16 + g4 + r;
        Pb[w][lrow * 32 + cl] = f2bf(p0);
        Pb[w][lrow * 32 + 16 + cl] = f2bf(p1);
      }
    }
    bf16x8 pa[4];
#pragma unroll
    for (int li = 0; li < 4; ++li)
      pa[li] = *(const bf16x8*)&Pb[w][(li * 16 + cl) * 32 + g8];
#pragma unroll
    for (int di = 0; di < 4; ++di) {
      bf16x8 bv;
#pragma unroll
      for (int e = 0; e < 8; ++e)
        bv[e] = (short)Vs[w][(g8 + e) * 64 + di * 16 + cl];
#pragma unroll
      for (int li = 0; li < 4; ++li)
        acc_o[li][di] = MFMA16(pa[li], bv, acc_o[li][di]);
    }
  }
  const int part = c * 4 + w;   // 0..15
  const size_t obase = (((size_t)(b * 16 + h)) * 16 + part) * 4096;
#pragma unroll
  for (int li = 0; li < 4; ++li)
#pragma unroll
    for (int di = 0; di < 4; ++di)
#pragma unroll
      for (int r = 0; r < 4; ++r)
        Opart[obase + (size_t)(li * 16 + g4 + r) * 64 + di * 16 + cl] = acc_o[li][di][r];
  if (cl == 0) {
    const size_t mb = (((size_t)(b * 16 + h)) * 16 + part) * 128;
#pragma unroll
    for (int li = 0; li < 4; ++li)
#pragma unroll
      for (int r = 0; r < 4; ++r) {
        ml[mb + li * 16 + g4 + r] = m_r[li][r];
        ml[mb + 64 + li * 16 + g4 + r] = l_r[li][r];
      }
  }
}

// ---------------------------------------------------------------- combine 16 partials per (b,h)
__global__ __launch_bounds__(256) void combine_kernel(
    const float* __restrict__ Opart, const float* __restrict__ ml,
    float* __restrict__ attn_out) {
  const int id = blockIdx.x * 256 + threadIdx.x;   // 524288
  const int d = id & 63;
  const int l = (id >> 6) & 63;
  const int h = (id >> 12) & 15;
  const int b = id >> 16;
  const size_t bh = (size_t)(b * 16 + h);
  float M = -INFINITY;
#pragma unroll
  for (int p = 0; p < 16; ++p) M = fmaxf(M, ml[(bh * 16 + p) * 128 + l]);
  float t = 0.f, acc = 0.f;
#pragma unroll
  for (int p = 0; p < 16; ++p) {
    const float mp = ml[(bh * 16 + p) * 128 + l];
    const float lp = ml[(bh * 16 + p) * 128 + 64 + l];
    const float wgt = __expf(mp - M);
    t += lp * wgt;
    acc += wgt * Opart[(bh * 16 + p) * 4096 + l * 64 + d];
  }
  attn_out[((size_t)(b * 64 + l)) * 1024 + h * 64 + d] = acc / t;
}

// ---------------------------------------------------------------- out projection: C[512,1024] = A@W.T + b (fp32)
__global__ __launch_bounds__(256) void out_proj_kernel(
    const float* __restrict__ A, const float* __restrict__ Wt,
    const float* __restrict__ bias, float* __restrict__ C) {
  __shared__ float As[32 * 33];
  __shared__ float Bs[64 * 33];
  const int tid = threadIdx.x;
  const int m0 = (int)(blockIdx.x & 15) * 32;
  const int n0 = (int)(blockIdx.x >> 4) * 64;
  const int r0 = (tid >> 4) * 2;
  const int c0 = (tid & 15) * 4;
  float acc[2][4] = {};
  for (int k0 = 0; k0 < 1024; k0 += 32) {
    if (k0) __syncthreads();
    {
      const int row = tid >> 3, col = (tid & 7) * 4;
      const float4 a4 = *(const float4*)&A[(size_t)(m0 + row) * 1024 + k0 + col];
      As[row * 33 + col] = a4.x; As[row * 33 + col + 1] = a4.y;
      As[row * 33 + col + 2] = a4.z; As[row * 33 + col + 3] = a4.w;
    }
#pragma unroll
    for (int i = 0; i < 2; ++i) {
      const int e = i * 1024 + tid * 4;
      const int row = e >> 5, col = e & 31;
      const float4 b4 = *(const float4*)&Wt[(size_t)(n0 + row) * 1024 + k0 + col];
      Bs[row * 33 + col] = b4.x; Bs[row * 33 + col + 1] = b4.y;
      Bs[row * 33 + col + 2] = b4.z; Bs[row * 33 + col + 3] = b4.w;
    }
    __syncthreads();
#pragma unroll
    for (int kk = 0; kk < 32; ++kk) {
      const float a0 = As[r0 * 33 + kk], a1 = As[(r0 + 1) * 33 + kk];
      float bv[4];
#pragma unroll
      for (int j = 0; j < 4; ++j) bv[j] = Bs[(c0 + j) * 33 + kk];
#pragma unroll
      for (int j = 0; j < 4; ++j) {
        acc[0][j] = fmaf(a0, bv[j], acc[0][j]);
        acc[1][j] = fmaf(a1, bv[j], acc[1][j]);
      }
    }
  }
#pragma unroll
  for (int i = 0; i < 2; ++i)
#pragma unroll
    for (int j = 0; j < 4; ++j)
      C[(size_t)(m0 + r0 + i) * 1024 + n0 + c0 + j] = acc[i][j] + bias[n0 + c0 + j];
}

// ----------------------------------------------------------------
extern "C" void kernel_launch(void* const* d_in, const int* in_sizes, int n_in,
                              void* d_out, int out_size, void* d_ws, size_t ws_size,
                              hipStream_t stream) {
  (void)in_sizes; (void)n_in; (void)out_size; (void)ws_size;
  const float* x = (const float*)d_in[0];
  const float* latents = (const float*)d_in[1];
  const float* q_w = (const float*)d_in[2];
  const float* q_b = (const float*)d_in[3];
  const float* k_w = (const float*)d_in[4];
  const float* k_b = (const float*)d_in[5];
  const float* v_w = (const float*)d_in[6];
  const float* v_b = (const float*)d_in[7];
  const float* out_w = (const float*)d_in[8];
  const float* out_b = (const float*)d_in[9];
  float* out = (float*)d_out;

  // workspace layout (~236 MiB total)
  char* ws = (char*)d_ws;
  size_t off = 0;
  auto alloc = [&](size_t bytes) {
    char* p = ws + off;
    off += (bytes + 255) & ~(size_t)255;
    return p;
  };
  unsigned short* xbf   = (unsigned short*)alloc(33554432ull * 2);
  unsigned short* kwbf  = (unsigned short*)alloc(1048576ull * 2);
  unsigned short* vwbf  = (unsigned short*)alloc(1048576ull * 2);
  unsigned short* qwbf  = (unsigned short*)alloc(1048576ull * 2);
  unsigned short* latbf = (unsigned short*)alloc(65536ull * 2);
  unsigned short* lqbf  = (unsigned short*)alloc(65536ull * 2);
  float2*         cs    = (float2*)alloc(4096ull * 32 * 8);
  unsigned short* Kbf   = (unsigned short*)alloc(33554432ull * 2);
  unsigned short* Vbf   = (unsigned short*)alloc(33554432ull * 2);
  float*          Opart = (float*)alloc(8ull * 16 * 16 * 4096 * 4);
  float*          mlbuf = (float*)alloc(8ull * 16 * 16 * 128 * 4);
  float*          attn_out = (float*)alloc(512ull * 1024 * 4);

  cast_f32_bf16<<<2048, 256, 0, stream>>>(x, xbf, 33554432 / 4);
  cast_f32_bf16<<<512, 256, 0, stream>>>(k_w, kwbf, 1048576 / 4);
  cast_f32_bf16<<<512, 256, 0, stream>>>(v_w, vwbf, 1048576 / 4);
  cast_f32_bf16<<<512, 256, 0, stream>>>(q_w, qwbf, 1048576 / 4);
  cast_f32_bf16<<<64, 256, 0, stream>>>(latents, latbf, 65536 / 4);
  rope_table_kernel<<<512, 256, 0, stream>>>(cs);
  lq_mfma_kernel<<<8, 256, 0, stream>>>(latbf, qwbf, q_b, cs, lqbf);
  kv_proj_kernel<<<1024, 512, 0, stream>>>(xbf, kwbf, vwbf, k_b, v_b, cs, Kbf, Vbf);
  attn_kernel<<<512, 256, 0, stream>>>(lqbf, Kbf, Vbf, Opart, mlbuf);
  combine_kernel<<<2048, 256, 0, stream>>>(Opart, mlbuf, attn_out);
  out_proj_kernel<<<256, 256, 0, stream>>>(attn_out, out_w, out_b, out);
}